// Round 2
// baseline (336.728 us; speedup 1.0000x reference)
//
#include <hip/hip_runtime.h>
#include <stdint.h>

// Problem constants
#define F_     128
#define N_     12288
#define NH_    9
#define NSLOT_ 8
#define NVARS_ 8
#define NUP_   (4*N_)
#define K6_    (NH_*F_)   // 1152
#define NSTEP6 (K6_/64)   // 18

typedef __attribute__((ext_vector_type(8))) short bf16x8;
typedef __attribute__((ext_vector_type(4))) float f32x4;

typedef const __attribute__((address_space(1))) unsigned char* gp1_t;
typedef __attribute__((address_space(3))) unsigned char* lp3_t;

__device__ __forceinline__ void load16(const void* g, void* l) {
  __builtin_amdgcn_global_load_lds((gp1_t)g, (lp3_t)l, 16, 0, 0);
}

__device__ __forceinline__ unsigned short f2bf(float f) {
  union { float f; unsigned int u; } x; x.f = f;
  unsigned int u = x.u;
  unsigned int r = u + 0x7FFFu + ((u >> 16) & 1u);   // RNE
  return (unsigned short)(r >> 16);
}

// ---------------- converts ----------------
__global__ void k_conv_emb(const float4* __restrict__ src, ushort4* __restrict__ dst, int n4) {
  int i = blockIdx.x * blockDim.x + threadIdx.x;
  if (i >= n4) return;
  float4 v = src[i];
  ushort4 o;
  o.x = f2bf(v.x); o.y = f2bf(v.y); o.z = f2bf(v.z); o.w = f2bf(v.w);
  dst[i] = o;
}

// dst[j*rows + k] = bf16(src[k*cols + j]) ; dst is [cols][rows]
__global__ void k_transpose_bf(const float* __restrict__ src, unsigned short* __restrict__ dst,
                               int rows, int cols) {
  int i = blockIdx.x * blockDim.x + threadIdx.x;
  if (i >= rows * cols) return;
  int j = i / rows, k = i % rows;
  dst[i] = f2bf(src[k * cols + j]);
}

// ---------------- zoom 5 (unchanged from round 1; ~25us, near memory floor) ----------------
__global__ __launch_bounds__(256) void k_h5(
    const unsigned short* __restrict__ embB,
    const unsigned short* __restrict__ W5T,
    const float* __restrict__ b5,
    const float* __restrict__ x5,
    const int* __restrict__ var_idx,
    const int* __restrict__ adjc,
    float* __restrict__ y5)
{
  __shared__ __align__(1024) unsigned char smem[8192 + 32768 + 64*4];
  unsigned char* Asm = smem;
  unsigned char* Bsm = smem + 8192;
  int* ald = (int*)(smem + 8192 + 32768);

  const int tid = threadIdx.x;
  const int l = tid & 63, w = tid >> 6;
  const int wr = w >> 1, wc = w & 1;
  const int li8 = l >> 3, pc = l & 7, l15 = l & 15, l16 = l >> 4;

  const int nt = blockIdx.x, slot = blockIdx.y;
  const int n0 = nt * 64;
  const int var = var_idx[slot];

  if (tid < 64) ald[tid] = adjc[(n0 + tid) * NH_];
  __syncthreads();

  const f32x4 fz = {0.f, 0.f, 0.f, 0.f};
  f32x4 accS[2][4], accH[2][4];
#pragma unroll
  for (int mf = 0; mf < 2; ++mf)
#pragma unroll
    for (int nf = 0; nf < 4; ++nf) { accS[mf][nf] = fz; accH[mf][nf] = fz; }

  const size_t embVarOff = (size_t)var * ((size_t)N_ * F_);

  for (int step = 0; step < 2; ++step) {
    const int k0 = step << 6;
#pragma unroll
    for (int q2 = 0; q2 < 2; ++q2) {
      const int q = w * 2 + q2;
      const int r = q * 8 + li8;
      const int lc = pc ^ (r & 7);
      const unsigned short* g = embB + embVarOff + (size_t)ald[r] * F_ + k0 + lc * 8;
      load16(g, Asm + q * 1024);
    }
#pragma unroll
    for (int q2 = 0; q2 < 8; ++q2) {
      const int q = w * 8 + q2;
      const int j = q * 8 + li8;
      const int lc = pc ^ (j & 7);
      const unsigned short* g = W5T + (size_t)j * F_ + k0 + lc * 8;
      load16(g, Bsm + q * 1024);
    }
    __syncthreads();

#pragma unroll
    for (int kf = 0; kf < 2; ++kf) {
      const int kc = kf * 4 + l16;
      bf16x8 a[2], bs[4], bh[4];
#pragma unroll
      for (int mf = 0; mf < 2; ++mf) {
        const int r = wr * 32 + mf * 16 + l15;
        a[mf] = *(const bf16x8*)(Asm + r * 128 + ((kc ^ (r & 7)) << 4));
      }
#pragma unroll
      for (int nf = 0; nf < 4; ++nf) {
        const int js = wc * 64 + nf * 16 + l15;
        bs[nf] = *(const bf16x8*)(Bsm + js * 128 + ((kc ^ (js & 7)) << 4));
        const int jh = js + 128;
        bh[nf] = *(const bf16x8*)(Bsm + jh * 128 + ((kc ^ (jh & 7)) << 4));
      }
#pragma unroll
      for (int mf = 0; mf < 2; ++mf)
#pragma unroll
        for (int nf = 0; nf < 4; ++nf) {
          accS[mf][nf] = __builtin_amdgcn_mfma_f32_16x16x32_bf16(a[mf], bs[nf], accS[mf][nf], 0, 0, 0);
          accH[mf][nf] = __builtin_amdgcn_mfma_f32_16x16x32_bf16(a[mf], bh[nf], accH[mf][nf], 0, 0, 0);
        }
    }
    __syncthreads();
  }

#pragma unroll
  for (int mf = 0; mf < 2; ++mf)
#pragma unroll
    for (int nf = 0; nf < 4; ++nf) {
      const int f = wc * 64 + nf * 16 + l15;
      const float sb = b5[f];
      const float hb = b5[128 + f];
#pragma unroll
      for (int reg = 0; reg < 4; ++reg) {
        const int r = wr * 32 + mf * 16 + l16 * 4 + reg;
        const int n = n0 + r;
        const size_t idx = ((size_t)slot * N_ + n) * F_ + f;
        y5[idx] = x5[idx] * (accS[mf][nf][reg] + sb) + (accH[mf][nf][reg] + hb);
      }
    }
}

// ---------------- zoom 6: 256x256 tile, 4-phase pipelined K-loop ----------------
// 8 waves (2M x 4N). Per wave: rows {mh*128 + wr*64 ..+64}, cols {wc*32 scale, +128 shift}.
// LDS: A dbuf 2x32KB + B dbuf 2x32KB + ald. Half-tiles (128 rows) staged via
// global_load_lds w16; counted vmcnt(4) keeps 2-3 half-tiles in flight across barriers.
__global__ __launch_bounds__(512, 2) void k_h6(
    const unsigned short* __restrict__ embB,   // [NVARS][N][F] bf16
    const unsigned short* __restrict__ W6T,    // [1024][1152] bf16 (transposed W6)
    const float* __restrict__ b6,              // [1024]
    const float* __restrict__ x6,              // [NSLOT][NUP][F]
    const int* __restrict__ var_idx,
    const int* __restrict__ adjc,              // [N][9]
    float* __restrict__ y6)                    // [NSLOT][NUP][F]
{
  __shared__ __align__(1024) unsigned char smem[65536 + 65536 + 256*NH_*4];
  unsigned char* Asm0 = smem;                  // 2 x [256 rows x 128B], swizzled
  unsigned char* Bsm0 = smem + 65536;          // 2 x [256 rows x 128B], swizzled
  int* ald = (int*)(smem + 131072);            // 256 x 9 neighbor ids

  const int tid = threadIdx.x;
  const int l = tid & 63, w = tid >> 6;        // 8 waves
  const int wr = w >> 2, wc = w & 3;           // 2 x 4
  const int li8 = l >> 3, pc = l & 7, l15 = l & 15, l16 = l >> 4;

  // XCD-aware swizzle over flattened grid (1536 % 8 == 0 -> bijective)
  int bid = blockIdx.x + 48 * (blockIdx.y + 4 * blockIdx.z);
  bid = (bid & 7) * (1536 / 8) + (bid >> 3);
  const int nt = bid % 48;
  const int ct = (bid / 48) & 3;
  const int slot = bid / 192;

  const int n0 = nt * 256;
  const int col0 = ct * 256;
  const int var = var_idx[slot];
  const size_t embOff = (size_t)var * ((size_t)N_ * F_);

  for (int t2 = tid; t2 < 256 * NH_; t2 += 512) ald[t2] = adjc[n0 * NH_ + t2];
  __syncthreads();

#define STAGE_A(s, hh, bb) do {                                                   \
    const int h_ = (s) >> 1; const int kk_ = ((s) & 1) << 6;                      \
    _Pragma("unroll")                                                             \
    for (int q2_ = 0; q2_ < 2; ++q2_) {                                           \
      const int q_ = w * 2 + q2_;                                                 \
      const int rl_ = (hh) * 128 + q_ * 8 + li8;                                  \
      const int lc_ = pc ^ (rl_ & 7);                                             \
      const unsigned short* g_ = embB + embOff + (size_t)ald[rl_ * NH_ + h_] * F_ \
                                 + kk_ + lc_ * 8;                                 \
      load16(g_, Asm0 + (bb) * 32768 + (hh) * 16384 + q_ * 1024);                 \
    } } while (0)

#define STAGE_B(s, hh, bb) do {                                                   \
    const int k_ = (s) << 6;                                                      \
    _Pragma("unroll")                                                             \
    for (int q2_ = 0; q2_ < 2; ++q2_) {                                           \
      const int q_ = w * 2 + q2_;                                                 \
      const int jl_ = (hh) * 128 + q_ * 8 + li8;                                  \
      const int lc_ = pc ^ (jl_ & 7);                                             \
      const unsigned short* g_ = W6T + (size_t)(col0 + jl_) * K6_ + k_ + lc_ * 8; \
      load16(g_, Bsm0 + (bb) * 32768 + (hh) * 16384 + q_ * 1024);                 \
    } } while (0)

#define LDA(dst, mh) do {                                                         \
    _Pragma("unroll")                                                             \
    for (int mq_ = 0; mq_ < 4; ++mq_)                                             \
    _Pragma("unroll")                                                             \
    for (int kf_ = 0; kf_ < 2; ++kf_) {                                           \
      const int r_ = (mh) * 128 + wr * 64 + mq_ * 16 + l15;                       \
      const int kc_ = kf_ * 4 + l16;                                              \
      dst[mq_][kf_] = *(const bf16x8*)(Ab + r_ * 128 + ((kc_ ^ (r_ & 7)) << 4));  \
    } } while (0)

#define LDB(dst, jofs) do {                                                       \
    _Pragma("unroll")                                                             \
    for (int nf_ = 0; nf_ < 2; ++nf_)                                             \
    _Pragma("unroll")                                                             \
    for (int kf_ = 0; kf_ < 2; ++kf_) {                                           \
      const int j_ = (jofs) + wc * 32 + nf_ * 16 + l15;                           \
      const int kc_ = kf_ * 4 + l16;                                              \
      dst[nf_][kf_] = *(const bf16x8*)(Bb + j_ * 128 + ((kc_ ^ (j_ & 7)) << 4));  \
    } } while (0)

#define MM(acc, mh, af, bfr) do {                                                 \
    _Pragma("unroll")                                                             \
    for (int mq_ = 0; mq_ < 4; ++mq_)                                             \
    _Pragma("unroll")                                                             \
    for (int nf_ = 0; nf_ < 2; ++nf_)                                             \
    _Pragma("unroll")                                                             \
    for (int kf_ = 0; kf_ < 2; ++kf_)                                             \
      acc[(mh)*4+mq_][nf_] = __builtin_amdgcn_mfma_f32_16x16x32_bf16(             \
          af[mq_][kf_], bfr[nf_][kf_], acc[(mh)*4+mq_][nf_], 0, 0, 0);            \
    } while (0)

#define VMCNT4 asm volatile("s_waitcnt vmcnt(4)" ::: "memory")
#define LGK0   do { asm volatile("s_waitcnt lgkmcnt(0)" ::: "memory"); \
                    __builtin_amdgcn_sched_barrier(0); } while (0)
#define BAR    __builtin_amdgcn_s_barrier()
#define PRIO1  __builtin_amdgcn_s_setprio(1)
#define PRIO0  __builtin_amdgcn_s_setprio(0)

  const f32x4 fz = {0.f, 0.f, 0.f, 0.f};
  f32x4 accS[8][2], accH[8][2];
#pragma unroll
  for (int mf = 0; mf < 8; ++mf)
#pragma unroll
    for (int nf = 0; nf < 2; ++nf) { accS[mf][nf] = fz; accH[mf][nf] = fz; }

  // prologue: stage tile 0 (issue order == consumption order), leave B1,A1 in flight
  STAGE_A(0, 0, 0);
  STAGE_B(0, 0, 0);
  STAGE_B(0, 1, 0);
  STAGE_A(0, 1, 0);
  VMCNT4;  // A0(0), B0(0) landed
  BAR;

#pragma unroll 1
  for (int t = 0; t < NSTEP6; ++t) {
    const unsigned char* Ab = Asm0 + (t & 1) * 32768;
    const unsigned char* Bb = Bsm0 + (t & 1) * 32768;
    const int tn = (t == NSTEP6 - 1) ? 0 : t + 1;   // wrap: junk prefetch, never read
    const int bn = (t + 1) & 1;

    bf16x8 a[4][2], bS[2][2], bH[2][2];

    // phase 0: mh0 x S     (reads A-half0 + B-half0)
    LDA(a, 0);
    LDB(bS, 0);
    STAGE_A(tn, 0, bn);
    VMCNT4;            // B1(t) landed
    BAR; LGK0;
    PRIO1; MM(accS, 0, a, bS); PRIO0;
    BAR;

    // phase 1: mh0 x H     (reads B-half1)
    LDB(bH, 128);
    STAGE_B(tn, 0, bn);
    VMCNT4;            // A1(t) landed
    BAR; LGK0;
    PRIO1; MM(accH, 0, a, bH); PRIO0;
    BAR;

    // phase 2: mh1 x S     (reads A-half1; bS reused from regs)
    LDA(a, 1);
    STAGE_B(tn, 1, bn);
    BAR; LGK0;
    PRIO1; MM(accS, 1, a, bS); PRIO0;
    BAR;

    // phase 3: mh1 x H     (all from regs)
    STAGE_A(tn, 1, bn);
    VMCNT4;            // A0(t+1), B0(t+1) landed
    BAR; LGK0;
    PRIO1; MM(accH, 1, a, bH); PRIO0;
    BAR;
  }
  asm volatile("s_waitcnt vmcnt(0)" ::: "memory");

  // epilogue: FiLM
#pragma unroll
  for (int mh = 0; mh < 2; ++mh)
#pragma unroll
    for (int mq = 0; mq < 4; ++mq)
#pragma unroll
      for (int nf = 0; nf < 2; ++nf) {
        const int f = wc * 32 + nf * 16 + l15;
        const float sb = b6[col0 + f];
        const float hb = b6[col0 + 128 + f];
#pragma unroll
        for (int reg = 0; reg < 4; ++reg) {
          const int r = mh * 128 + wr * 64 + mq * 16 + l16 * 4 + reg;
          const int nup = 4 * (n0 + r) + ct;
          const size_t idx = ((size_t)slot * NUP_ + nup) * F_ + f;
          y6[idx] = x6[idx] * (accS[mh*4+mq][nf][reg] + sb) + (accH[mh*4+mq][nf][reg] + hb);
        }
      }

#undef STAGE_A
#undef STAGE_B
#undef LDA
#undef LDB
#undef MM
#undef VMCNT4
#undef LGK0
#undef BAR
#undef PRIO1
#undef PRIO0
}

extern "C" void kernel_launch(void* const* d_in, const int* in_sizes, int n_in,
                              void* d_out, int out_size, void* d_ws, size_t ws_size,
                              hipStream_t stream) {
  (void)in_sizes; (void)n_in; (void)out_size; (void)ws_size;
  const float* emb = (const float*)d_in[0];
  const float* x5  = (const float*)d_in[1];
  const float* x6  = (const float*)d_in[2];
  const float* W5  = (const float*)d_in[3];
  const float* b5  = (const float*)d_in[4];
  const float* W6  = (const float*)d_in[5];
  const float* b6  = (const float*)d_in[6];
  const int* var_idx = (const int*)d_in[7];
  const int* adjc    = (const int*)d_in[8];

  float* y5 = (float*)d_out;
  float* y6 = y5 + (size_t)NSLOT_ * N_ * F_;

  unsigned short* embB = (unsigned short*)d_ws;
  unsigned short* W5T  = embB + (size_t)NVARS_ * N_ * F_;
  unsigned short* W6T  = W5T + 256 * 128;

  const int embN4 = NVARS_ * N_ * F_ / 4;
  k_conv_emb<<<(embN4 + 255) / 256, 256, 0, stream>>>((const float4*)emb, (ushort4*)embB, embN4);
  k_transpose_bf<<<(128 * 256 + 255) / 256, 256, 0, stream>>>(W5, W5T, 128, 256);
  k_transpose_bf<<<(1152 * 1024 + 255) / 256, 256, 0, stream>>>(W6, W6T, 1152, 1024);

  k_h5<<<dim3(N_ / 64, NSLOT_), 256, 0, stream>>>(embB, W5T, b5, x5, var_idx, adjc, y5);
  k_h6<<<dim3(48, 4, 8), 512, 0, stream>>>(embB, W6T, b6, x6, var_idx, adjc, y6);
}